// Round 1
// baseline (45.523 us; speedup 1.0000x reference)
//
#include <hip/hip_runtime.h>
#include <math.h>

#define TB 2048
#define TK 128
#define TD 512
#define BROWS 8
#define DC 64

// Kernel A: det_sf[k] = -0.5 * sum_d log(|D[k,d]| + 1e-8)
__global__ __launch_bounds__(64) void det_kernel(const float* __restrict__ Dm,
                                                 float* __restrict__ det_sf) {
    int k = blockIdx.x;
    int lane = threadIdx.x;
    float s = 0.f;
    for (int i = lane; i < TD; i += 64) {
        s += logf(fabsf(Dm[(size_t)k * TD + i]) + 1e-8f);
    }
    #pragma unroll
    for (int m = 32; m >= 1; m >>= 1) s += __shfl_xor(s, m, 64);
    if (lane == 0) det_sf[k] = -0.5f * s;
}

// Kernel B: fused Mahalanobis + log-softmax + argmax/dist.
// 256 threads, 8 rows/block, thread = 1 row x 4 consecutive k.
__global__ __launch_bounds__(256, 2) void gmm_kernel(const float* __restrict__ x,
        const float* __restrict__ C, const float* __restrict__ Dm,
        const float* __restrict__ det_sf, float* __restrict__ out) {
    __shared__ float xs[BROWS][TD];   // 16 KB
    __shared__ float sa[DC][TK];      // 32 KB : u = rsqrt(|D|+eps), layout [d][k]
    __shared__ float sb[DC][TK];      // 32 KB : c*u, layout [d][k]

    const int tid = threadIdx.x;
    const int b0 = blockIdx.x * BROWS;

    // Load x tile (8 rows x 512) coalesced as float4.
    {
        const float4* xg = reinterpret_cast<const float4*>(x + (size_t)b0 * TD);
        float4* xsv = reinterpret_cast<float4*>(&xs[0][0]);
        #pragma unroll
        for (int i = 0; i < (BROWS * TD / 4) / 256; ++i)  // 4 iters
            xsv[tid + i * 256] = xg[tid + i * 256];
    }

    const int kg = tid & 31;      // k-group 0..31
    const int k0 = kg * 4;        // first of 4 k's
    const int row = tid >> 5;     // 0..7

    float acc0 = 0.f, acc1 = 0.f, acc2 = 0.f, acc3 = 0.f;

    // staging mapping: kk = k-row (0..127), dh = 0/32 half of the d-chunk
    const int kk = tid >> 1;
    const int dh = (tid & 1) * 32;

    for (int dc = 0; dc < TD; dc += DC) {
        __syncthreads();  // protect previous chunk reads
        // Stage chunk: compute u and c*u on the fly, transpose into [d][k].
        const float4* Dg = reinterpret_cast<const float4*>(Dm + (size_t)kk * TD + dc + dh);
        const float4* Cg = reinterpret_cast<const float4*>(C  + (size_t)kk * TD + dc + dh);
        #pragma unroll
        for (int j = 0; j < 8; ++j) {
            float4 dv = Dg[j];
            float4 cv = Cg[j];
            int dbase = dh + j * 4;
            float da, us;
            da = fabsf(dv.x) + 1e-8f; us = rsqrtf(da); sa[dbase + 0][kk] = us; sb[dbase + 0][kk] = cv.x * us;
            da = fabsf(dv.y) + 1e-8f; us = rsqrtf(da); sa[dbase + 1][kk] = us; sb[dbase + 1][kk] = cv.y * us;
            da = fabsf(dv.z) + 1e-8f; us = rsqrtf(da); sa[dbase + 2][kk] = us; sb[dbase + 2][kk] = cv.z * us;
            da = fabsf(dv.w) + 1e-8f; us = rsqrtf(da); sa[dbase + 3][kk] = us; sb[dbase + 3][kk] = cv.w * us;
        }
        __syncthreads();
        // Compute: acc += (u*x - u*c)^2 over this d-chunk.
        const float* xrow = &xs[row][dc];
        #pragma unroll 4
        for (int d = 0; d < DC; ++d) {
            float xv = xrow[d];
            float4 a4 = *reinterpret_cast<const float4*>(&sa[d][k0]);
            float4 b4 = *reinterpret_cast<const float4*>(&sb[d][k0]);
            float t;
            t = fmaf(xv, a4.x, -b4.x); acc0 = fmaf(t, t, acc0);
            t = fmaf(xv, a4.y, -b4.y); acc1 = fmaf(t, t, acc1);
            t = fmaf(xv, a4.z, -b4.z); acc2 = fmaf(t, t, acc2);
            t = fmaf(xv, a4.w, -b4.w); acc3 = fmaf(t, t, acc3);
        }
    }

    // Epilogue: s[k] = det_sf[k] - 0.5*dist_sq[k]; log-softmax over k per row.
    float4 dsf = *reinterpret_cast<const float4*>(&det_sf[k0]);
    float s0 = fmaf(-0.5f, acc0, dsf.x);
    float s1 = fmaf(-0.5f, acc1, dsf.y);
    float s2 = fmaf(-0.5f, acc2, dsf.z);
    float s3 = fmaf(-0.5f, acc3, dsf.w);

    // Row reductions across 32 lanes (half-wave butterflies; masks<=16 stay in half).
    float mrow = fmaxf(fmaxf(s0, s1), fmaxf(s2, s3));
    #pragma unroll
    for (int msk = 16; msk >= 1; msk >>= 1) mrow = fmaxf(mrow, __shfl_xor(mrow, msk, 64));

    float p0 = expf(s0 - mrow), p1 = expf(s1 - mrow);
    float p2 = expf(s2 - mrow), p3 = expf(s3 - mrow);
    float psum = (p0 + p1) + (p2 + p3);
    #pragma unroll
    for (int msk = 16; msk >= 1; msk >>= 1) psum += __shfl_xor(psum, msk, 64);
    float lse = logf(psum) + mrow;

    const float LOGC = -18.420680743952367f;  // ln(1e-8)
    float4 o;
    o.x = fmaxf(s0 - lse, LOGC);
    o.y = fmaxf(s1 - lse, LOGC);
    o.z = fmaxf(s2 - lse, LOGC);
    o.w = fmaxf(s3 - lse, LOGC);
    const int b = b0 + row;
    *reinterpret_cast<float4*>(&out[(size_t)b * TK + k0]) = o;

    // Argmax (max value, first index on ties) carrying dist_sq.
    float bv = s0; int bi = k0; float bd = acc0;
    if (s1 > bv) { bv = s1; bi = k0 + 1; bd = acc1; }
    if (s2 > bv) { bv = s2; bi = k0 + 2; bd = acc2; }
    if (s3 > bv) { bv = s3; bi = k0 + 3; bd = acc3; }
    #pragma unroll
    for (int msk = 16; msk >= 1; msk >>= 1) {
        float ov = __shfl_xor(bv, msk, 64);
        int   oi = __shfl_xor(bi, msk, 64);
        float od = __shfl_xor(bd, msk, 64);
        if (ov > bv || (ov == bv && oi < bi)) { bv = ov; bi = oi; bd = od; }
    }
    if (kg == 0) out[(size_t)TB * TK + b] = sqrtf(bd);
}

extern "C" void kernel_launch(void* const* d_in, const int* in_sizes, int n_in,
                              void* d_out, int out_size, void* d_ws, size_t ws_size,
                              hipStream_t stream) {
    const float* x  = (const float*)d_in[0];
    const float* C  = (const float*)d_in[1];
    const float* Dm = (const float*)d_in[2];
    float* out = (float*)d_out;
    float* det_sf = (float*)d_ws;  // 128 floats

    det_kernel<<<TK, 64, 0, stream>>>(Dm, det_sf);
    gmm_kernel<<<TB / BROWS, 256, 0, stream>>>(x, C, Dm, det_sf, out);
}

// Round 2
// 27.402 us; speedup vs baseline: 1.6613x; 1.6613x over previous
//
#include <hip/hip_runtime.h>
#include <math.h>

#define TB 2048
#define TK 128
#define TD 512

// ---------------------------------------------------------------------------
// Kernel P: per-class params, transposed for the main kernel.
//   uT[d][k]  = rsqrt(|D[k][d]| + 1e-8)
//   cuT[d][k] = C[k][d] * uT[d][k]
//   det_sf[k] = sum_d log(uT)   ( == -0.5 * sum_d log(|D|+eps) )
// ---------------------------------------------------------------------------
__global__ __launch_bounds__(64) void prep_kernel(const float* __restrict__ Dm,
        const float* __restrict__ C, float* __restrict__ uT,
        float* __restrict__ cuT, float* __restrict__ det_sf) {
    const int k = blockIdx.x;
    const int lane = threadIdx.x;
    float lsum = 0.f;
    #pragma unroll
    for (int i = 0; i < TD / 64; ++i) {
        int d = lane + i * 64;
        float u = rsqrtf(fabsf(Dm[k * TD + d]) + 1e-8f);
        uT[d * TK + k] = u;
        cuT[d * TK + k] = C[k * TD + d] * u;
        lsum += logf(u);
    }
    #pragma unroll
    for (int m = 32; m >= 1; m >>= 1) lsum += __shfl_xor(lsum, m, 64);
    if (lane == 0) det_sf[k] = lsum;
}

// ---------------------------------------------------------------------------
// Main kernel: partial Mahalanobis dist_sq over a d-slice.
// 256 threads = 32 k-groups (4 k each) x 8 row-groups (R rows each).
// part[ds][b][k] += sum over this block's d-range of (u*x - c*u)^2
// ---------------------------------------------------------------------------
template<int R, int DSPLIT>
__global__ __launch_bounds__(256, 2) void dist_kernel(const float* __restrict__ x,
        const float* __restrict__ uT, const float* __restrict__ cuT,
        float* __restrict__ part) {
    constexpr int BROWS = 8 * R;
    constexpr int DLEN = TD / DSPLIT;
    constexpr int DC = 64;
    constexpr int NCH = DLEN / DC;

    __shared__ float xs[BROWS][DLEN];   // 16 KB (BROWS*DLEN == 4096 always)
    __shared__ float sa[DC][TK];        // 32 KB
    __shared__ float sb[DC][TK];        // 32 KB

    const int tid = threadIdx.x;
    const int rb = blockIdx.x / DSPLIT;
    const int ds = blockIdx.x % DSPLIT;
    const int b0 = rb * BROWS;
    const int dstart = ds * DLEN;

    // Load x tile (coalesced float4).
    {
        constexpr int F4PERROW = DLEN / 4;
        #pragma unroll
        for (int i = 0; i < (BROWS * F4PERROW) / 256; ++i) {  // 4 iters
            int idx = tid + i * 256;
            int row = idx / F4PERROW;
            int c4 = idx % F4PERROW;
            *reinterpret_cast<float4*>(&xs[row][c4 * 4]) =
                *reinterpret_cast<const float4*>(
                    &x[(size_t)(b0 + row) * TD + dstart + c4 * 4]);
        }
    }

    const int kg = tid & 31;
    const int k0 = kg * 4;
    const int rowbase = (tid >> 5) * R;

    float acc[R][4];
    #pragma unroll
    for (int r = 0; r < R; ++r)
        #pragma unroll
        for (int j = 0; j < 4; ++j) acc[r][j] = 0.f;

    for (int c = 0; c < NCH; ++c) {
        if (c) __syncthreads();  // WAR on sa/sb
        // Stage params for this d-chunk: contiguous 32 KB each, coalesced.
        {
            const float4* srcA = reinterpret_cast<const float4*>(
                uT + (size_t)(dstart + c * DC) * TK);
            const float4* srcB = reinterpret_cast<const float4*>(
                cuT + (size_t)(dstart + c * DC) * TK);
            float4* dstA = reinterpret_cast<float4*>(&sa[0][0]);
            float4* dstB = reinterpret_cast<float4*>(&sb[0][0]);
            #pragma unroll
            for (int i = 0; i < (DC * TK / 4) / 256; ++i) {  // 8 iters
                dstA[tid + i * 256] = srcA[tid + i * 256];
                dstB[tid + i * 256] = srcB[tid + i * 256];
            }
        }
        __syncthreads();

        const int dbase = c * DC;
        #pragma unroll 2
        for (int d4 = 0; d4 < DC; d4 += 4) {
            float4 xv[R];
            #pragma unroll
            for (int r = 0; r < R; ++r)
                xv[r] = *reinterpret_cast<const float4*>(&xs[rowbase + r][dbase + d4]);
            #pragma unroll
            for (int dd = 0; dd < 4; ++dd) {
                float4 a4 = *reinterpret_cast<const float4*>(&sa[d4 + dd][k0]);
                float4 b4 = *reinterpret_cast<const float4*>(&sb[d4 + dd][k0]);
                #pragma unroll
                for (int r = 0; r < R; ++r) {
                    float xvr = (&xv[r].x)[dd];
                    float t;
                    t = fmaf(xvr, a4.x, -b4.x); acc[r][0] = fmaf(t, t, acc[r][0]);
                    t = fmaf(xvr, a4.y, -b4.y); acc[r][1] = fmaf(t, t, acc[r][1]);
                    t = fmaf(xvr, a4.z, -b4.z); acc[r][2] = fmaf(t, t, acc[r][2]);
                    t = fmaf(xvr, a4.w, -b4.w); acc[r][3] = fmaf(t, t, acc[r][3]);
                }
            }
        }
    }

    #pragma unroll
    for (int r = 0; r < R; ++r) {
        float4 v = make_float4(acc[r][0], acc[r][1], acc[r][2], acc[r][3]);
        *reinterpret_cast<float4*>(
            &part[((size_t)ds * TB + b0 + rowbase + r) * TK + k0]) = v;
    }
}

// ---------------------------------------------------------------------------
// Epilogue: combine partials, log-softmax over k, argmax + dist.
// 4 waves/block, 1 row per wave, lane handles k = 2*lane, 2*lane+1.
// NOTE: no __restrict__ — part may alias out when DSPLIT==1.
// ---------------------------------------------------------------------------
__global__ __launch_bounds__(256) void finish_kernel(const float* part,
        const float* det_sf, float* out, int dsplit) {
    const int lane = threadIdx.x & 63;
    const int wv = threadIdx.x >> 6;
    const int b = blockIdx.x * 4 + wv;
    const int k0 = lane * 2;

    float d0 = 0.f, d1 = 0.f;
    for (int s = 0; s < dsplit; ++s) {
        float2 p = *reinterpret_cast<const float2*>(
            &part[((size_t)s * TB + b) * TK + k0]);
        d0 += p.x; d1 += p.y;
    }
    float2 dsf = *reinterpret_cast<const float2*>(&det_sf[k0]);
    float s0 = fmaf(-0.5f, d0, dsf.x);
    float s1 = fmaf(-0.5f, d1, dsf.y);

    float m = fmaxf(s0, s1);
    #pragma unroll
    for (int msk = 32; msk >= 1; msk >>= 1) m = fmaxf(m, __shfl_xor(m, msk, 64));
    float p0 = expf(s0 - m), p1 = expf(s1 - m);
    float ps = p0 + p1;
    #pragma unroll
    for (int msk = 32; msk >= 1; msk >>= 1) ps += __shfl_xor(ps, msk, 64);
    float lse = logf(ps) + m;

    const float LOGC = -18.420680743952367f;  // ln(1e-8)
    float2 o;
    o.x = fmaxf(s0 - lse, LOGC);
    o.y = fmaxf(s1 - lse, LOGC);
    *reinterpret_cast<float2*>(&out[(size_t)b * TK + k0]) = o;

    // Argmax over s (first index wins ties), carrying dist_sq.
    float bv; int bi; float bd;
    if (s1 > s0) { bv = s1; bi = k0 + 1; bd = d1; }
    else         { bv = s0; bi = k0;     bd = d0; }
    #pragma unroll
    for (int msk = 32; msk >= 1; msk >>= 1) {
        float ov = __shfl_xor(bv, msk, 64);
        int   oi = __shfl_xor(bi, msk, 64);
        float od = __shfl_xor(bd, msk, 64);
        if (ov > bv || (ov == bv && oi < bi)) { bv = ov; bi = oi; bd = od; }
    }
    if (lane == 0) out[(size_t)TB * TK + b] = sqrtf(bd);
}

// ---------------------------------------------------------------------------
extern "C" void kernel_launch(void* const* d_in, const int* in_sizes, int n_in,
                              void* d_out, int out_size, void* d_ws, size_t ws_size,
                              hipStream_t stream) {
    const float* x  = (const float*)d_in[0];
    const float* C  = (const float*)d_in[1];
    const float* Dm = (const float*)d_in[2];
    float* out = (float*)d_out;

    const size_t MB = 1ull << 20;
    const size_t paramsBytes = (size_t)TD * TK * 4 * 2 + TK * 4 + 256;  // uT+cuT+det

    char* w = (char*)d_ws;
    int dsplit;
    float* part;
    if (ws_size >= 8 * MB + paramsBytes)      dsplit = 8;
    else if (ws_size >= 4 * MB + paramsBytes) dsplit = 4;
    else if (ws_size >= 2 * MB + paramsBytes) dsplit = 2;
    else                                      dsplit = 1;

    size_t partBytes;
    if (dsplit == 1) {
        part = out;  // dist_sq written into resp region, finished in-place
        partBytes = 0;
    } else {
        part = (float*)w;
        partBytes = (size_t)dsplit * MB;
    }
    float* uT  = (float*)(w + partBytes);
    float* cuT = uT + (size_t)TD * TK;
    float* dsf = cuT + (size_t)TD * TK;

    prep_kernel<<<TK, 64, 0, stream>>>(Dm, C, uT, cuT, dsf);

    switch (dsplit) {
        case 8: dist_kernel<8, 8><<<(TB / 64) * 8, 256, 0, stream>>>(x, uT, cuT, part); break;
        case 4: dist_kernel<4, 4><<<(TB / 32) * 4, 256, 0, stream>>>(x, uT, cuT, part); break;
        case 2: dist_kernel<2, 2><<<(TB / 16) * 2, 256, 0, stream>>>(x, uT, cuT, part); break;
        default: dist_kernel<2, 1><<<(TB / 16) * 1, 256, 0, stream>>>(x, uT, cuT, part); break;
    }

    finish_kernel<<<TB / 4, 256, 0, stream>>>(part, dsf, out, dsplit);
}